// Round 2
// baseline (1668.839 us; speedup 1.0000x reference)
//
#include <hip/hip_runtime.h>
#include <math.h>

#define N_ROWS 262144
#define K_CODES 1024
#define D_DIM 64
#define WL_CAP 262144   // == N_ROWS: overflow (silently-wrong rows) impossible

typedef __attribute__((ext_vector_type(8))) short short8;
typedef __attribute__((ext_vector_type(4))) float f32x4;
typedef unsigned short ushortT;
typedef unsigned int uintT;

// bf16 round-to-nearest-even of a finite fp32, returned as raw bf16 bits.
__device__ inline uintT bf16_rne_bits(float v) {
    uintT u = __float_as_uint(v);
    return (u + 0x7FFFu + ((u >> 16) & 1u)) >> 16;
}

// ---------------------------------------------------------------------------
// Prep: c_sq (EXACT same accumulation order as the validated kernel),
// codebook bf16 hi/lo split, counter zero.
// ---------------------------------------------------------------------------
__global__ __launch_bounds__(64) void prep_kernel(const float* __restrict__ cb,
                                                  ushortT* __restrict__ cbh,
                                                  ushortT* __restrict__ cbl,
                                                  float* __restrict__ c_sq,
                                                  int* __restrict__ cnt) {
    if (blockIdx.x == 0 && threadIdx.x == 0) *cnt = 0;
    int k = blockIdx.x * 64 + threadIdx.x;
    if (k >= K_CODES) return;
    const float4* row = (const float4*)(cb + (size_t)k * D_DIM);
    float s = 0.0f;
#pragma unroll
    for (int j = 0; j < D_DIM / 4; ++j) {
        float4 v = row[j];
        s = fmaf(v.x, v.x, s);
        s = fmaf(v.y, v.y, s);
        s = fmaf(v.z, v.z, s);
        s = fmaf(v.w, v.w, s);
        float e[4] = {v.x, v.y, v.z, v.w};
#pragma unroll
        for (int q = 0; q < 4; ++q) {
            int d = 4 * j + q;
            uintT hb = bf16_rne_bits(e[q]);
            float hif = __uint_as_float(hb << 16);
            uintT lb = bf16_rne_bits(e[q] - hif);
            cbh[(size_t)k * D_DIM + d] = (ushortT)hb;
            cbl[(size_t)k * D_DIM + d] = (ushortT)lb;
        }
    }
    c_sq[k] = s;
}

// ---------------------------------------------------------------------------
// Coarse kernel, round 2: MAX TLP.
//  - LDS cut from 39 KB to ~5 KB (dropped the x-row stage; epilogue re-reads
//    x from global, which is L3-hot -- we have 98% memory headroom).
//  - __launch_bounds__(256, 8): VGPR <= 64 (round-1 build used 60), so all
//    2048 blocks co-resident: 8 blocks/CU = 32 waves/CU, doubling the
//    waves/SIMD available to hide the ~L3-latency B-fragment stalls that
//    round 1 showed (both pipes <25% busy, HBM 1.5% => latency-bound).
//  - Main loop unchanged: barrier-free, register double-buffered global B
//    loads, packed sortable-int min-tracking (validated absmax 0.0).
// ---------------------------------------------------------------------------
__global__ __launch_bounds__(256, 8) void coarse_kernel(
        const float* __restrict__ x_all, const float* __restrict__ cb,
        const ushortT* __restrict__ cbh, const ushortT* __restrict__ cbl,
        const float* __restrict__ c_sq_g,
        float* __restrict__ out_idx, float* __restrict__ out_res,
        float* __restrict__ out_emb, int* __restrict__ cnt,
        int* __restrict__ wl) {
    __shared__ float csq_s[K_CODES];  // 4 KB
    __shared__ float xsq_s[128];
    __shared__ int   idx_s[128];

    const int t  = threadIdx.x;
    const int w  = t >> 6;          // wave 0..3
    const int L  = t & 63;          // lane
    const int q  = L >> 4;          // quad 0..3
    const int n  = L & 15;          // class / col
    const int rowbase = blockIdx.x * 128 + w * 32;

    // ---- B fragment bases; issue tiles 0/1 early (in flight during A prep)
    const ushortT* bh_base = cbh + (size_t)n * D_DIM + q * 8;
    const ushortT* bl_base = cbl + (size_t)n * D_DIM + q * 8;
    short8 a_h0 = *(const short8*)(bh_base + 0);
    short8 a_h1 = *(const short8*)(bh_base + 32);
    short8 a_l0 = *(const short8*)(bl_base + 0);
    short8 a_l1 = *(const short8*)(bl_base + 32);
    short8 b_h0 = *(const short8*)(bh_base + 1024);
    short8 b_h1 = *(const short8*)(bh_base + 1024 + 32);
    short8 b_l0 = *(const short8*)(bl_base + 1024);
    short8 b_l1 = *(const short8*)(bl_base + 1024 + 32);

    // ---- c_sq -> LDS (once per block)
    ((float4*)csq_s)[t] = ((const float4*)c_sq_g)[t];

    // ---- load + convert A fragments (x rows), x_sq ----
    short8 ah[2][2], al[2][2];
#pragma unroll
    for (int s = 0; s < 2; ++s) {
        float part = 0.0f;
#pragma unroll
        for (int kt = 0; kt < 2; ++kt) {
            const float4* p = (const float4*)(x_all +
                (size_t)(rowbase + s * 16 + n) * D_DIM + kt * 32 + q * 8);
            float4 v0 = p[0], v1 = p[1];
            float e[8] = {v0.x, v0.y, v0.z, v0.w, v1.x, v1.y, v1.z, v1.w};
#pragma unroll
            for (int j = 0; j < 8; ++j) {
                part = fmaf(e[j], e[j], part);
                uintT hb = bf16_rne_bits(e[j]);
                float hif = __uint_as_float(hb << 16);
                uintT lb = bf16_rne_bits(e[j] - hif);
                ah[s][kt][j] = (short)hb;
                al[s][kt][j] = (short)lb;
            }
        }
        part += __shfl_xor(part, 16);
        part += __shfl_xor(part, 32);
        if (q == 0) xsq_s[w * 32 + s * 16 + n] = part;
    }
    __syncthreads();   // csq_s visible

    // ---- packed trackers: per (rowset s, reg j). INT_MIN = -inf sentinel.
    int m1p[2][4], m2p[2][4];
#pragma unroll
    for (int s = 0; s < 2; ++s)
#pragma unroll
        for (int j = 0; j < 4; ++j) { m1p[s][j] = (int)0x80000000; m2p[s][j] = (int)0x80000000; }

    auto tile_step = [&](int tl, const short8& bh0, const short8& bh1,
                         const short8& bl0, const short8& bl1) {
        f32x4 acc0 = {0.f, 0.f, 0.f, 0.f};
        f32x4 acc1 = {0.f, 0.f, 0.f, 0.f};
        // EXACT same 12-MFMA order as the validated kernel
        acc0 = __builtin_amdgcn_mfma_f32_16x16x32_bf16(ah[0][0], bh0, acc0, 0, 0, 0);
        acc1 = __builtin_amdgcn_mfma_f32_16x16x32_bf16(ah[1][0], bh0, acc1, 0, 0, 0);
        acc0 = __builtin_amdgcn_mfma_f32_16x16x32_bf16(ah[0][1], bh1, acc0, 0, 0, 0);
        acc1 = __builtin_amdgcn_mfma_f32_16x16x32_bf16(ah[1][1], bh1, acc1, 0, 0, 0);
        acc0 = __builtin_amdgcn_mfma_f32_16x16x32_bf16(ah[0][0], bl0, acc0, 0, 0, 0);
        acc1 = __builtin_amdgcn_mfma_f32_16x16x32_bf16(ah[1][0], bl0, acc1, 0, 0, 0);
        acc0 = __builtin_amdgcn_mfma_f32_16x16x32_bf16(ah[0][1], bl1, acc0, 0, 0, 0);
        acc1 = __builtin_amdgcn_mfma_f32_16x16x32_bf16(ah[1][1], bl1, acc1, 0, 0, 0);
        acc0 = __builtin_amdgcn_mfma_f32_16x16x32_bf16(al[0][0], bh0, acc0, 0, 0, 0);
        acc1 = __builtin_amdgcn_mfma_f32_16x16x32_bf16(al[1][0], bh0, acc1, 0, 0, 0);
        acc0 = __builtin_amdgcn_mfma_f32_16x16x32_bf16(al[0][1], bh1, acc0, 0, 0, 0);
        acc1 = __builtin_amdgcn_mfma_f32_16x16x32_bf16(al[1][1], bh1, acc1, 0, 0, 0);

        float cv = csq_s[tl * 16 + n];
        uintT kcp = (uintT)(63 - tl);   // complement -> packed max == first occurrence
#pragma unroll
        for (int j = 0; j < 4; ++j) {
            float v0 = fmaf(2.0f, acc0[j], -cv);
            int u0 = (int)((__float_as_uint(v0) & 0xFFFFFFC0u) | kcp);
            m2p[0][j] = max(m2p[0][j], min(m1p[0][j], u0));
            m1p[0][j] = max(m1p[0][j], u0);
            float v1 = fmaf(2.0f, acc1[j], -cv);
            int u1 = (int)((__float_as_uint(v1) & 0xFFFFFFC0u) | kcp);
            m2p[1][j] = max(m2p[1][j], min(m1p[1][j], u1));
            m1p[1][j] = max(m1p[1][j], u1);
        }
    };

    // ---- main loop: 64 tiles, register double-buffered B, no barriers ----
    for (int tl = 0; tl < 64; tl += 2) {
        tile_step(tl, a_h0, a_h1, a_l0, a_l1);
        if (tl + 2 < 64) {
            size_t o = (size_t)(tl + 2) * 1024;
            a_h0 = *(const short8*)(bh_base + o);
            a_h1 = *(const short8*)(bh_base + o + 32);
            a_l0 = *(const short8*)(bl_base + o);
            a_l1 = *(const short8*)(bl_base + o + 32);
        }
        tile_step(tl + 1, b_h0, b_h1, b_l0, b_l1);
        if (tl + 3 < 64) {
            size_t o = (size_t)(tl + 3) * 1024;
            b_h0 = *(const short8*)(bh_base + o);
            b_h1 = *(const short8*)(bh_base + o + 32);
            b_l0 = *(const short8*)(bl_base + o);
            b_l1 = *(const short8*)(bl_base + o + 32);
        }
    }

    // ---- decode + butterfly reduce across the 16 classes (max-space) ----
#pragma unroll
    for (int s = 0; s < 2; ++s)
#pragma unroll
        for (int j = 0; j < 4; ++j) {
            int p1 = m1p[s][j], p2 = m2p[s][j];
            float a1 = __uint_as_float((uintT)p1 & 0xFFFFFFC0u);
            float a2 = __uint_as_float((uintT)p2 & 0xFFFFFFC0u);
            int ai = ((63 - (p1 & 63)) << 4) | n;   // idx = tl*16 + n
#pragma unroll
            for (int msk = 1; msk < 16; msk <<= 1) {
                float o1 = __shfl_xor(a1, msk);
                float o2 = __shfl_xor(a2, msk);
                int oi = __shfl_xor(ai, msk);
                float nm2 = fmaxf(fminf(a1, o1), fmaxf(a2, o2));
                bool take = (o1 > a1) || (o1 == a1 && oi < ai);
                a1 = take ? o1 : a1;
                ai = take ? oi : ai;
                a2 = nm2;
            }
            if (n == 0) {
                int rl = w * 32 + s * 16 + q * 4 + j;
                float xsq = xsq_s[rl];
                float xn = sqrtf(xsq);
                // 2*margin (validated: 8e-5*xn + 4e-4) + 2*quant (2^-12)
                float thr = fmaf(8.0e-5f, xn, 6.44140625e-4f);
                bool fb = ((a1 - a2) <= thr) || (a2 < 0.0f) || (xsq > 170.0f);
                idx_s[rl] = ai | (fb ? (1 << 30) : 0);
            }
        }
    __syncthreads();

    // ---- outputs ----
    if (t < 128) {
        int e = idx_s[t];
        int row = blockIdx.x * 128 + t;
        out_idx[row] = (float)(e & 0x3FFFFFFF);
        if (e >> 30) {
            int pos = atomicAdd(cnt, 1);
            if (pos < WL_CAP) wl[pos] = row;
        }
    }
    {
        int lr = t >> 1;
        int row = blockIdx.x * 128 + lr;
        int seg = (t & 1) * 32;
        int id = idx_s[lr] & 0x3FFFFFFF;
        const float4* xs = (const float4*)(x_all + (size_t)row * D_DIM + seg);
        const float4* cs = (const float4*)(cb + (size_t)id * D_DIM + seg);
        float4* rs = (float4*)(out_res + (size_t)row * D_DIM + seg);
        float4* es = (float4*)(out_emb + (size_t)row * D_DIM + seg);
#pragma unroll
        for (int j = 0; j < 8; ++j) {
            float4 xv = xs[j], cv = cs[j];
            float4 rv;
            rv.x = xv.x - cv.x; rv.y = xv.y - cv.y;
            rv.z = xv.z - cv.z; rv.w = xv.w - cv.w;
            rs[j] = rv;
            es[j] = cv;
        }
    }
}

// ---------------------------------------------------------------------------
// Fallback: exact fp32 rescan of worklist rows (unchanged, validated).
// ---------------------------------------------------------------------------
__global__ __launch_bounds__(256) void fallback_kernel(
        const float* __restrict__ x_all, const float* __restrict__ cb,
        const float* __restrict__ c_sq, const int* __restrict__ wl,
        const int* __restrict__ cnt,
        float* __restrict__ out_idx, float* __restrict__ out_res,
        float* __restrict__ out_emb) {
    int count = *cnt;
    if (count > WL_CAP) count = WL_CAP;
    const int L = threadIdx.x & 63;
    const int waveId = blockIdx.x * 4 + (threadIdx.x >> 6);
    const int nWaves = gridDim.x * 4;

    for (int i = waveId; i < count; i += nWaves) {
        int r = wl[i];

        float x[D_DIM];
        const float4* xr = (const float4*)(x_all + (size_t)r * D_DIM);
#pragma unroll
        for (int j = 0; j < D_DIM / 4; ++j) {
            float4 v = xr[j];
            x[4 * j + 0] = v.x; x[4 * j + 1] = v.y;
            x[4 * j + 2] = v.z; x[4 * j + 3] = v.w;
        }
        float x_sq = 0.0f;
#pragma unroll
        for (int d = 0; d < D_DIM; ++d) x_sq = fmaf(x[d], x[d], x_sq);

        float best = INFINITY;
        int bidx = 0x7FFFFFFF;
        for (int kk = 0; kk < 16; ++kk) {
            int k = kk * 64 + L;
            const float* c0 = cb + (size_t)k * D_DIM;
            float a00 = 0.f, a01 = 0.f, a02 = 0.f, a03 = 0.f;
#pragma unroll
            for (int j = 0; j < 4; ++j) {
                float4 v0 = *(const float4*)(c0 + 16 * j + 0);
                float4 v1 = *(const float4*)(c0 + 16 * j + 4);
                float4 v2 = *(const float4*)(c0 + 16 * j + 8);
                float4 v3 = *(const float4*)(c0 + 16 * j + 12);
                float* a = (j == 0) ? &a00 : (j == 1) ? &a01 : (j == 2) ? &a02 : &a03;
                float acc = *a;
                acc = fmaf(x[16 * j + 0],  v0.x, acc);
                acc = fmaf(x[16 * j + 1],  v0.y, acc);
                acc = fmaf(x[16 * j + 2],  v0.z, acc);
                acc = fmaf(x[16 * j + 3],  v0.w, acc);
                acc = fmaf(x[16 * j + 4],  v1.x, acc);
                acc = fmaf(x[16 * j + 5],  v1.y, acc);
                acc = fmaf(x[16 * j + 6],  v1.z, acc);
                acc = fmaf(x[16 * j + 7],  v1.w, acc);
                acc = fmaf(x[16 * j + 8],  v2.x, acc);
                acc = fmaf(x[16 * j + 9],  v2.y, acc);
                acc = fmaf(x[16 * j + 10], v2.z, acc);
                acc = fmaf(x[16 * j + 11], v2.w, acc);
                acc = fmaf(x[16 * j + 12], v3.x, acc);
                acc = fmaf(x[16 * j + 13], v3.y, acc);
                acc = fmaf(x[16 * j + 14], v3.z, acc);
                acc = fmaf(x[16 * j + 15], v3.w, acc);
                *a = acc;
            }
            float dot = (a00 + a01) + (a02 + a03);
            float d = (x_sq - 2.0f * dot) + c_sq[k];
            if (d < best) { best = d; bidx = k; }
        }

#pragma unroll
        for (int msk = 1; msk < 64; msk <<= 1) {
            float ob = __shfl_xor(best, msk);
            int oi = __shfl_xor(bidx, msk);
            bool take = (ob < best) || (ob == best && oi < bidx);
            best = take ? ob : best;
            bidx = take ? oi : bidx;
        }

        if (L < 16) {
            const float4* cbest = (const float4*)(cb + (size_t)bidx * D_DIM);
            float4 c = cbest[L];
            float4 v;
            v.x = x[4 * L + 0] - c.x; v.y = x[4 * L + 1] - c.y;
            v.z = x[4 * L + 2] - c.z; v.w = x[4 * L + 3] - c.w;
            ((float4*)(out_res + (size_t)r * D_DIM))[L] = v;
            ((float4*)(out_emb + (size_t)r * D_DIM))[L] = c;
            if (L == 0) out_idx[r] = (float)bidx;
        }
    }
}

extern "C" void kernel_launch(void* const* d_in, const int* in_sizes, int n_in,
                              void* d_out, int out_size, void* d_ws, size_t ws_size,
                              hipStream_t stream) {
    const float* x  = (const float*)d_in[0];
    const float* cb = (const float*)d_in[1];

    char* base = (char*)d_ws;
    ushortT* cbh = (ushortT*)base;                         // 128 KB
    ushortT* cbl = (ushortT*)(base + 131072);              // 128 KB
    float*   csq = (float*)(base + 262144);                // 4 KB
    int*     cnt = (int*)(base + 266240);
    int*     wl  = (int*)(base + 266256);                  // 1 MB (cap == N)

    float* out   = (float*)d_out;
    float* o_idx = out;
    float* o_res = out + (size_t)N_ROWS;
    float* o_emb = o_res + (size_t)N_ROWS * D_DIM;

    prep_kernel<<<16, 64, 0, stream>>>(cb, cbh, cbl, csq, cnt);
    coarse_kernel<<<N_ROWS / 128, 256, 0, stream>>>(x, cb, cbh, cbl, csq,
                                                    o_idx, o_res, o_emb, cnt, wl);
    fallback_kernel<<<1024, 256, 0, stream>>>(x, cb, csq, wl, cnt,
                                              o_idx, o_res, o_emb);
}

// Round 5
// 586.432 us; speedup vs baseline: 2.8457x; 2.8457x over previous
//
#include <hip/hip_runtime.h>
#include <math.h>

#define N_ROWS 262144
#define K_CODES 1024
#define D_DIM 64
#define WL_CAP 262144   // == N_ROWS: overflow (silently-wrong rows) impossible

typedef __attribute__((ext_vector_type(8))) short short8;
typedef __attribute__((ext_vector_type(4))) float f32x4;
typedef unsigned short ushortT;
typedef unsigned int uintT;

// bf16 round-to-nearest-even of a finite fp32, returned as raw bf16 bits.
__device__ inline uintT bf16_rne_bits(float v) {
    uintT u = __float_as_uint(v);
    return (u + 0x7FFFu + ((u >> 16) & 1u)) >> 16;
}

// ---------------------------------------------------------------------------
// Prep: c_sq (EXACT same accumulation order as the validated kernel),
// codebook bf16 hi/lo split, counter zero.
// ---------------------------------------------------------------------------
__global__ __launch_bounds__(64) void prep_kernel(const float* __restrict__ cb,
                                                  ushortT* __restrict__ cbh,
                                                  ushortT* __restrict__ cbl,
                                                  float* __restrict__ c_sq,
                                                  int* __restrict__ cnt) {
    if (blockIdx.x == 0 && threadIdx.x == 0) *cnt = 0;
    int k = blockIdx.x * 64 + threadIdx.x;
    if (k >= K_CODES) return;
    const float4* row = (const float4*)(cb + (size_t)k * D_DIM);
    float s = 0.0f;
#pragma unroll
    for (int j = 0; j < D_DIM / 4; ++j) {
        float4 v = row[j];
        s = fmaf(v.x, v.x, s);
        s = fmaf(v.y, v.y, s);
        s = fmaf(v.z, v.z, s);
        s = fmaf(v.w, v.w, s);
        float e[4] = {v.x, v.y, v.z, v.w};
#pragma unroll
        for (int q = 0; q < 4; ++q) {
            int d = 4 * j + q;
            uintT hb = bf16_rne_bits(e[q]);
            float hif = __uint_as_float(hb << 16);
            uintT lb = bf16_rne_bits(e[q] - hif);
            cbh[(size_t)k * D_DIM + d] = (ushortT)hb;
            cbl[(size_t)k * D_DIM + d] = (ushortT)lb;
        }
    }
    c_sq[k] = s;
}

// ---------------------------------------------------------------------------
// Coarse kernel, round 5 (= round-4 resubmit; round-4 bench was an infra
// failure, kernel never ran): REAL register pipelining.
//  - __launch_bounds__(256,3) -> 170-reg budget so the prefetch pipeline can
//    actually live in registers (round-1's 60-reg build collapsed it into a
//    serial load->wait->compute chain; round-2's 64-reg bound spilled).
//  - Prefetch DISTANCE 4 with 4 named buffer sets: 16 loads in flight/wave,
//    issue-to-wait distance ~3 tile_steps.
//  - Non-temporal x loads + output stores: the 190 MB stream no longer
//    thrashes the 4 MB per-XCD L2, keeping the 512 KB split codebook
//    L2-resident (shorter latency to hide).
//  - Arithmetic identical to the validated round-1 kernel (absmax 0.0).
// ---------------------------------------------------------------------------
__global__ __launch_bounds__(256, 3) void coarse_kernel(
        const float* __restrict__ x_all, const float* __restrict__ cb,
        const ushortT* __restrict__ cbh, const ushortT* __restrict__ cbl,
        const float* __restrict__ c_sq_g,
        float* __restrict__ out_idx, float* __restrict__ out_res,
        float* __restrict__ out_emb, int* __restrict__ cnt,
        int* __restrict__ wl) {
    __shared__ float csq_s[K_CODES];  // 4 KB
    __shared__ float xsq_s[128];
    __shared__ int   idx_s[128];

    const int t  = threadIdx.x;
    const int w  = t >> 6;          // wave 0..3
    const int L  = t & 63;          // lane
    const int q  = L >> 4;          // quad 0..3
    const int n  = L & 15;          // class / col
    const int rowbase = blockIdx.x * 128 + w * 32;

    // ---- B fragment bases; prefetch tiles 0..3 (16 loads in flight) ----
    const ushortT* bh_base = cbh + (size_t)n * D_DIM + q * 8;
    const ushortT* bl_base = cbl + (size_t)n * D_DIM + q * 8;
    short8 b0h0 = *(const short8*)(bh_base + 0);
    short8 b0h1 = *(const short8*)(bh_base + 32);
    short8 b0l0 = *(const short8*)(bl_base + 0);
    short8 b0l1 = *(const short8*)(bl_base + 32);
    short8 b1h0 = *(const short8*)(bh_base + 1024);
    short8 b1h1 = *(const short8*)(bh_base + 1024 + 32);
    short8 b1l0 = *(const short8*)(bl_base + 1024);
    short8 b1l1 = *(const short8*)(bl_base + 1024 + 32);
    short8 b2h0 = *(const short8*)(bh_base + 2048);
    short8 b2h1 = *(const short8*)(bh_base + 2048 + 32);
    short8 b2l0 = *(const short8*)(bl_base + 2048);
    short8 b2l1 = *(const short8*)(bl_base + 2048 + 32);
    short8 b3h0 = *(const short8*)(bh_base + 3072);
    short8 b3h1 = *(const short8*)(bh_base + 3072 + 32);
    short8 b3l0 = *(const short8*)(bl_base + 3072);
    short8 b3l1 = *(const short8*)(bl_base + 3072 + 32);

    // ---- c_sq -> LDS (once per block)
    ((float4*)csq_s)[t] = ((const float4*)c_sq_g)[t];

    // ---- load + convert A fragments (x rows), x_sq (non-temporal x) ----
    short8 ah[2][2], al[2][2];
#pragma unroll
    for (int s = 0; s < 2; ++s) {
        float part = 0.0f;
#pragma unroll
        for (int kt = 0; kt < 2; ++kt) {
            const f32x4* p = (const f32x4*)(x_all +
                (size_t)(rowbase + s * 16 + n) * D_DIM + kt * 32 + q * 8);
            f32x4 v0 = __builtin_nontemporal_load(p);
            f32x4 v1 = __builtin_nontemporal_load(p + 1);
            float e[8] = {v0[0], v0[1], v0[2], v0[3], v1[0], v1[1], v1[2], v1[3]};
#pragma unroll
            for (int j = 0; j < 8; ++j) {
                part = fmaf(e[j], e[j], part);
                uintT hb = bf16_rne_bits(e[j]);
                float hif = __uint_as_float(hb << 16);
                uintT lb = bf16_rne_bits(e[j] - hif);
                ah[s][kt][j] = (short)hb;
                al[s][kt][j] = (short)lb;
            }
        }
        part += __shfl_xor(part, 16);
        part += __shfl_xor(part, 32);
        if (q == 0) xsq_s[w * 32 + s * 16 + n] = part;
    }
    __syncthreads();   // csq_s visible

    // ---- packed trackers: per (rowset s, reg j). INT_MIN = -inf sentinel.
    int m1p[2][4], m2p[2][4];
#pragma unroll
    for (int s = 0; s < 2; ++s)
#pragma unroll
        for (int j = 0; j < 4; ++j) { m1p[s][j] = (int)0x80000000; m2p[s][j] = (int)0x80000000; }

    auto tile_step = [&](int tl, const short8& bh0, const short8& bh1,
                         const short8& bl0, const short8& bl1) {
        f32x4 acc0 = {0.f, 0.f, 0.f, 0.f};
        f32x4 acc1 = {0.f, 0.f, 0.f, 0.f};
        // EXACT same 12-MFMA order as the validated kernel
        acc0 = __builtin_amdgcn_mfma_f32_16x16x32_bf16(ah[0][0], bh0, acc0, 0, 0, 0);
        acc1 = __builtin_amdgcn_mfma_f32_16x16x32_bf16(ah[1][0], bh0, acc1, 0, 0, 0);
        acc0 = __builtin_amdgcn_mfma_f32_16x16x32_bf16(ah[0][1], bh1, acc0, 0, 0, 0);
        acc1 = __builtin_amdgcn_mfma_f32_16x16x32_bf16(ah[1][1], bh1, acc1, 0, 0, 0);
        acc0 = __builtin_amdgcn_mfma_f32_16x16x32_bf16(ah[0][0], bl0, acc0, 0, 0, 0);
        acc1 = __builtin_amdgcn_mfma_f32_16x16x32_bf16(ah[1][0], bl0, acc1, 0, 0, 0);
        acc0 = __builtin_amdgcn_mfma_f32_16x16x32_bf16(ah[0][1], bl1, acc0, 0, 0, 0);
        acc1 = __builtin_amdgcn_mfma_f32_16x16x32_bf16(ah[1][1], bl1, acc1, 0, 0, 0);
        acc0 = __builtin_amdgcn_mfma_f32_16x16x32_bf16(al[0][0], bh0, acc0, 0, 0, 0);
        acc1 = __builtin_amdgcn_mfma_f32_16x16x32_bf16(al[1][0], bh0, acc1, 0, 0, 0);
        acc0 = __builtin_amdgcn_mfma_f32_16x16x32_bf16(al[0][1], bh1, acc0, 0, 0, 0);
        acc1 = __builtin_amdgcn_mfma_f32_16x16x32_bf16(al[1][1], bh1, acc1, 0, 0, 0);

        float cv = csq_s[tl * 16 + n];
        uintT kcp = (uintT)(63 - tl);   // complement -> packed max == first occurrence
#pragma unroll
        for (int j = 0; j < 4; ++j) {
            float v0 = fmaf(2.0f, acc0[j], -cv);
            int u0 = (int)((__float_as_uint(v0) & 0xFFFFFFC0u) | kcp);
            m2p[0][j] = max(m2p[0][j], min(m1p[0][j], u0));
            m1p[0][j] = max(m1p[0][j], u0);
            float v1 = fmaf(2.0f, acc1[j], -cv);
            int u1 = (int)((__float_as_uint(v1) & 0xFFFFFFC0u) | kcp);
            m2p[1][j] = max(m2p[1][j], min(m1p[1][j], u1));
            m1p[1][j] = max(m1p[1][j], u1);
        }
    };

    // ---- main loop: 64 tiles, 4 buffer sets, prefetch distance 4 ----
    for (int tl = 0; tl < 64; tl += 4) {
        tile_step(tl, b0h0, b0h1, b0l0, b0l1);
        if (tl + 4 < 64) {
            size_t o = (size_t)(tl + 4) * 1024;
            b0h0 = *(const short8*)(bh_base + o);
            b0h1 = *(const short8*)(bh_base + o + 32);
            b0l0 = *(const short8*)(bl_base + o);
            b0l1 = *(const short8*)(bl_base + o + 32);
        }
        tile_step(tl + 1, b1h0, b1h1, b1l0, b1l1);
        if (tl + 5 < 64) {
            size_t o = (size_t)(tl + 5) * 1024;
            b1h0 = *(const short8*)(bh_base + o);
            b1h1 = *(const short8*)(bh_base + o + 32);
            b1l0 = *(const short8*)(bl_base + o);
            b1l1 = *(const short8*)(bl_base + o + 32);
        }
        tile_step(tl + 2, b2h0, b2h1, b2l0, b2l1);
        if (tl + 6 < 64) {
            size_t o = (size_t)(tl + 6) * 1024;
            b2h0 = *(const short8*)(bh_base + o);
            b2h1 = *(const short8*)(bh_base + o + 32);
            b2l0 = *(const short8*)(bl_base + o);
            b2l1 = *(const short8*)(bl_base + o + 32);
        }
        tile_step(tl + 3, b3h0, b3h1, b3l0, b3l1);
        if (tl + 7 < 64) {
            size_t o = (size_t)(tl + 7) * 1024;
            b3h0 = *(const short8*)(bh_base + o);
            b3h1 = *(const short8*)(bh_base + o + 32);
            b3l0 = *(const short8*)(bl_base + o);
            b3l1 = *(const short8*)(bl_base + o + 32);
        }
    }

    // ---- decode + butterfly reduce across the 16 classes (max-space) ----
#pragma unroll
    for (int s = 0; s < 2; ++s)
#pragma unroll
        for (int j = 0; j < 4; ++j) {
            int p1 = m1p[s][j], p2 = m2p[s][j];
            float a1 = __uint_as_float((uintT)p1 & 0xFFFFFFC0u);
            float a2 = __uint_as_float((uintT)p2 & 0xFFFFFFC0u);
            int ai = ((63 - (p1 & 63)) << 4) | n;   // idx = tl*16 + n
#pragma unroll
            for (int msk = 1; msk < 16; msk <<= 1) {
                float o1 = __shfl_xor(a1, msk);
                float o2 = __shfl_xor(a2, msk);
                int oi = __shfl_xor(ai, msk);
                float nm2 = fmaxf(fminf(a1, o1), fmaxf(a2, o2));
                bool take = (o1 > a1) || (o1 == a1 && oi < ai);
                a1 = take ? o1 : a1;
                ai = take ? oi : ai;
                a2 = nm2;
            }
            if (n == 0) {
                int rl = w * 32 + s * 16 + q * 4 + j;
                float xsq = xsq_s[rl];
                float xn = sqrtf(xsq);
                // 2*margin (validated: 8e-5*xn + 4e-4) + 2*quant (2^-12)
                float thr = fmaf(8.0e-5f, xn, 6.44140625e-4f);
                bool fb = ((a1 - a2) <= thr) || (a2 < 0.0f) || (xsq > 170.0f);
                idx_s[rl] = ai | (fb ? (1 << 30) : 0);
            }
        }
    __syncthreads();

    // ---- outputs (non-temporal stores: pure stream, keep L2 for codebook) ----
    if (t < 128) {
        int e = idx_s[t];
        int row = blockIdx.x * 128 + t;
        __builtin_nontemporal_store((float)(e & 0x3FFFFFFF), out_idx + row);
        if (e >> 30) {
            int pos = atomicAdd(cnt, 1);
            if (pos < WL_CAP) wl[pos] = row;
        }
    }
    {
        int lr = t >> 1;
        int row = blockIdx.x * 128 + lr;
        int seg = (t & 1) * 32;
        int id = idx_s[lr] & 0x3FFFFFFF;
        const f32x4* xs = (const f32x4*)(x_all + (size_t)row * D_DIM + seg);
        const f32x4* cs = (const f32x4*)(cb + (size_t)id * D_DIM + seg);
        f32x4* rs = (f32x4*)(out_res + (size_t)row * D_DIM + seg);
        f32x4* es = (f32x4*)(out_emb + (size_t)row * D_DIM + seg);
#pragma unroll
        for (int j = 0; j < 8; ++j) {
            f32x4 xv = __builtin_nontemporal_load(xs + j);
            f32x4 cv = cs[j];
            f32x4 rv = xv - cv;
            __builtin_nontemporal_store(rv, rs + j);
            __builtin_nontemporal_store(cv, es + j);
        }
    }
}

// ---------------------------------------------------------------------------
// Fallback: exact fp32 rescan of worklist rows (unchanged, validated).
// ---------------------------------------------------------------------------
__global__ __launch_bounds__(256) void fallback_kernel(
        const float* __restrict__ x_all, const float* __restrict__ cb,
        const float* __restrict__ c_sq, const int* __restrict__ wl,
        const int* __restrict__ cnt,
        float* __restrict__ out_idx, float* __restrict__ out_res,
        float* __restrict__ out_emb) {
    int count = *cnt;
    if (count > WL_CAP) count = WL_CAP;
    const int L = threadIdx.x & 63;
    const int waveId = blockIdx.x * 4 + (threadIdx.x >> 6);
    const int nWaves = gridDim.x * 4;

    for (int i = waveId; i < count; i += nWaves) {
        int r = wl[i];

        float x[D_DIM];
        const float4* xr = (const float4*)(x_all + (size_t)r * D_DIM);
#pragma unroll
        for (int j = 0; j < D_DIM / 4; ++j) {
            float4 v = xr[j];
            x[4 * j + 0] = v.x; x[4 * j + 1] = v.y;
            x[4 * j + 2] = v.z; x[4 * j + 3] = v.w;
        }
        float x_sq = 0.0f;
#pragma unroll
        for (int d = 0; d < D_DIM; ++d) x_sq = fmaf(x[d], x[d], x_sq);

        float best = INFINITY;
        int bidx = 0x7FFFFFFF;
        for (int kk = 0; kk < 16; ++kk) {
            int k = kk * 64 + L;
            const float* c0 = cb + (size_t)k * D_DIM;
            float a00 = 0.f, a01 = 0.f, a02 = 0.f, a03 = 0.f;
#pragma unroll
            for (int j = 0; j < 4; ++j) {
                float4 v0 = *(const float4*)(c0 + 16 * j + 0);
                float4 v1 = *(const float4*)(c0 + 16 * j + 4);
                float4 v2 = *(const float4*)(c0 + 16 * j + 8);
                float4 v3 = *(const float4*)(c0 + 16 * j + 12);
                float* a = (j == 0) ? &a00 : (j == 1) ? &a01 : (j == 2) ? &a02 : &a03;
                float acc = *a;
                acc = fmaf(x[16 * j + 0],  v0.x, acc);
                acc = fmaf(x[16 * j + 1],  v0.y, acc);
                acc = fmaf(x[16 * j + 2],  v0.z, acc);
                acc = fmaf(x[16 * j + 3],  v0.w, acc);
                acc = fmaf(x[16 * j + 4],  v1.x, acc);
                acc = fmaf(x[16 * j + 5],  v1.y, acc);
                acc = fmaf(x[16 * j + 6],  v1.z, acc);
                acc = fmaf(x[16 * j + 7],  v1.w, acc);
                acc = fmaf(x[16 * j + 8],  v2.x, acc);
                acc = fmaf(x[16 * j + 9],  v2.y, acc);
                acc = fmaf(x[16 * j + 10], v2.z, acc);
                acc = fmaf(x[16 * j + 11], v2.w, acc);
                acc = fmaf(x[16 * j + 12], v3.x, acc);
                acc = fmaf(x[16 * j + 13], v3.y, acc);
                acc = fmaf(x[16 * j + 14], v3.z, acc);
                acc = fmaf(x[16 * j + 15], v3.w, acc);
                *a = acc;
            }
            float dot = (a00 + a01) + (a02 + a03);
            float d = (x_sq - 2.0f * dot) + c_sq[k];
            if (d < best) { best = d; bidx = k; }
        }

#pragma unroll
        for (int msk = 1; msk < 64; msk <<= 1) {
            float ob = __shfl_xor(best, msk);
            int oi = __shfl_xor(bidx, msk);
            bool take = (ob < best) || (ob == best && oi < bidx);
            best = take ? ob : best;
            bidx = take ? oi : bidx;
        }

        if (L < 16) {
            const float4* cbest = (const float4*)(cb + (size_t)bidx * D_DIM);
            float4 c = cbest[L];
            float4 v;
            v.x = x[4 * L + 0] - c.x; v.y = x[4 * L + 1] - c.y;
            v.z = x[4 * L + 2] - c.z; v.w = x[4 * L + 3] - c.w;
            ((float4*)(out_res + (size_t)r * D_DIM))[L] = v;
            ((float4*)(out_emb + (size_t)r * D_DIM))[L] = c;
            if (L == 0) out_idx[r] = (float)bidx;
        }
    }
}

extern "C" void kernel_launch(void* const* d_in, const int* in_sizes, int n_in,
                              void* d_out, int out_size, void* d_ws, size_t ws_size,
                              hipStream_t stream) {
    const float* x  = (const float*)d_in[0];
    const float* cb = (const float*)d_in[1];

    char* base = (char*)d_ws;
    ushortT* cbh = (ushortT*)base;                         // 128 KB
    ushortT* cbl = (ushortT*)(base + 131072);              // 128 KB
    float*   csq = (float*)(base + 262144);                // 4 KB
    int*     cnt = (int*)(base + 266240);
    int*     wl  = (int*)(base + 266256);                  // 1 MB (cap == N)

    float* out   = (float*)d_out;
    float* o_idx = out;
    float* o_res = out + (size_t)N_ROWS;
    float* o_emb = o_res + (size_t)N_ROWS * D_DIM;

    prep_kernel<<<16, 64, 0, stream>>>(cb, cbh, cbl, csq, cnt);
    coarse_kernel<<<N_ROWS / 128, 256, 0, stream>>>(x, cb, cbh, cbl, csq,
                                                    o_idx, o_res, o_emb, cnt, wl);
    fallback_kernel<<<1024, 256, 0, stream>>>(x, cb, csq, wl, cnt,
                                              o_idx, o_res, o_emb);
}

// Round 6
// 451.245 us; speedup vs baseline: 3.6983x; 1.2996x over previous
//
#include <hip/hip_runtime.h>
#include <math.h>

#define N_ROWS 262144
#define K_CODES 1024
#define D_DIM 64
#define WL_CAP 262144   // == N_ROWS: overflow (silently-wrong rows) impossible

typedef __attribute__((ext_vector_type(8))) short short8;
typedef __attribute__((ext_vector_type(4))) float f32x4;
typedef unsigned short ushortT;
typedef unsigned int uintT;

// bf16 round-to-nearest-even of a finite fp32, returned as raw bf16 bits.
__device__ inline uintT bf16_rne_bits(float v) {
    uintT u = __float_as_uint(v);
    return (u + 0x7FFFu + ((u >> 16) & 1u)) >> 16;
}

// ---------------------------------------------------------------------------
// Prep: c_sq (EXACT same accumulation order as the validated kernel),
// codebook bf16 hi/lo split, counter zero.
// ---------------------------------------------------------------------------
__global__ __launch_bounds__(64) void prep_kernel(const float* __restrict__ cb,
                                                  ushortT* __restrict__ cbh,
                                                  ushortT* __restrict__ cbl,
                                                  float* __restrict__ c_sq,
                                                  int* __restrict__ cnt) {
    if (blockIdx.x == 0 && threadIdx.x == 0) *cnt = 0;
    int k = blockIdx.x * 64 + threadIdx.x;
    if (k >= K_CODES) return;
    const float4* row = (const float4*)(cb + (size_t)k * D_DIM);
    float s = 0.0f;
#pragma unroll
    for (int j = 0; j < D_DIM / 4; ++j) {
        float4 v = row[j];
        s = fmaf(v.x, v.x, s);
        s = fmaf(v.y, v.y, s);
        s = fmaf(v.z, v.z, s);
        s = fmaf(v.w, v.w, s);
        float e[4] = {v.x, v.y, v.z, v.w};
#pragma unroll
        for (int q = 0; q < 4; ++q) {
            int d = 4 * j + q;
            uintT hb = bf16_rne_bits(e[q]);
            float hif = __uint_as_float(hb << 16);
            uintT lb = bf16_rne_bits(e[q] - hif);
            cbh[(size_t)k * D_DIM + d] = (ushortT)hb;
            cbl[(size_t)k * D_DIM + d] = (ushortT)lb;
        }
    }
    c_sq[k] = s;
}

// ---------------------------------------------------------------------------
// Coarse kernel, round 6: validated round-0 LDS skeleton (lane-linear stage,
// 0 bank conflicts, reg-prefetch) with its serial-path costs removed:
//  - 64 codes/round (16 rounds), pre[4]=16 regs genuinely in flight;
//    LDS 21 KB (was 34); csq_s loaded ONCE (was per-round).
//  - 12 MFMAs/tile restructured: 2 chains of depth 6 -> 4 independent
//    chains of depth 3 (+1 f32x4 add per rowset). Halves the MFMA
//    dependent-latency path per tile.
//  - launch_bounds(256,4): 128-reg budget, ~100 needed -> no spill
//    (round-2 showed what forcing 64 does; rounds 1/5 showed named reg
//    buffers beyond budget silently collapse to serial loads).
//  - All nt hints reverted (round-5: nt stores 4x'd WRITE_SIZE to 455 MB).
//  - Numerics: same bf16 split / packed tracking / thresholds (absmax 0.0
//    in rounds 1 & 5 runs); acc regrouping error << validated margin.
// ---------------------------------------------------------------------------
__global__ __launch_bounds__(256, 4) void coarse_kernel(
        const float* __restrict__ x_all, const float* __restrict__ cb,
        const ushortT* __restrict__ cbh, const ushortT* __restrict__ cbl,
        const float* __restrict__ c_sq_g,
        float* __restrict__ out_idx, float* __restrict__ out_res,
        float* __restrict__ out_emb, int* __restrict__ cnt,
        int* __restrict__ wl) {
    __shared__ __align__(16) ushortT stage[8192];   // 16 KB: 64 codes (4 tiles), hi+lo
    __shared__ float csq_s[K_CODES];                // 4 KB
    __shared__ float xsq_s[128];
    __shared__ int   idx_s[128];

    const int t  = threadIdx.x;
    const int w  = t >> 6;          // wave 0..3
    const int L  = t & 63;          // lane
    const int q  = L >> 4;          // quad 0..3
    const int n  = L & 15;          // class / col
    const int rowbase = blockIdx.x * 128 + w * 32;

    // ---- c_sq -> LDS (ONCE; visible after first round barrier)
    ((float4*)csq_s)[t] = ((const float4*)c_sq_g)[t];

    // ---- load + convert A fragments (x rows), x_sq (validated round-1 code)
    short8 ah[2][2], al[2][2];
#pragma unroll
    for (int s = 0; s < 2; ++s) {
        float part = 0.0f;
#pragma unroll
        for (int kt = 0; kt < 2; ++kt) {
            const float4* p = (const float4*)(x_all +
                (size_t)(rowbase + s * 16 + n) * D_DIM + kt * 32 + q * 8);
            float4 v0 = p[0], v1 = p[1];
            float e[8] = {v0.x, v0.y, v0.z, v0.w, v1.x, v1.y, v1.z, v1.w};
#pragma unroll
            for (int j = 0; j < 8; ++j) {
                part = fmaf(e[j], e[j], part);
                uintT hb = bf16_rne_bits(e[j]);
                float hif = __uint_as_float(hb << 16);
                uintT lb = bf16_rne_bits(e[j] - hif);
                ah[s][kt][j] = (short)hb;
                al[s][kt][j] = (short)lb;
            }
        }
        part += __shfl_xor(part, 16);
        part += __shfl_xor(part, 32);
        if (q == 0) xsq_s[w * 32 + s * 16 + n] = part;
    }

    // ---- prologue: prefetch round 0 (64 codes, hi+lo = 16 KB) into regs ----
    uint4 pre[4];
#pragma unroll
    for (int i = 0; i < 4; ++i) {
        int c = i * 256 + t;                 // chunk 0..1023 (16 B each)
        int tile = c >> 8, inner = c & 255;
        int hilo = inner >> 7, cc = inner & 127;
        int kt = cc >> 6, LL = cc & 63;
        const ushortT* src = hilo ? cbl : cbh;
        size_t elem = (size_t)(tile * 16 + (LL & 15)) * D_DIM + kt * 32 + (LL >> 4) * 8;
        pre[i] = *(const uint4*)(src + elem);
    }

    // ---- packed trackers (validated): INT_MIN sentinel ----
    int m1p[2][4], m2p[2][4];
#pragma unroll
    for (int s = 0; s < 2; ++s)
#pragma unroll
        for (int j = 0; j < 4; ++j) { m1p[s][j] = (int)0x80000000; m2p[s][j] = (int)0x80000000; }

    // ---- main loop: 16 rounds x 4 tiles ----
    for (int r = 0; r < 16; ++r) {
        __syncthreads();                     // previous round's compute done
#pragma unroll
        for (int i = 0; i < 4; ++i)
            *(uint4*)(stage + (size_t)(i * 256 + t) * 8) = pre[i];
        __syncthreads();                     // staging (and csq at r=0) visible

        if (r < 15) {                        // prefetch next round, overlaps compute
            int rn = r + 1;
#pragma unroll
            for (int i = 0; i < 4; ++i) {
                int c = i * 256 + t;
                int tile = c >> 8, inner = c & 255;
                int hilo = inner >> 7, cc = inner & 127;
                int kt = cc >> 6, LL = cc & 63;
                const ushortT* src = hilo ? cbl : cbh;
                size_t elem = (size_t)(rn * 64 + tile * 16 + (LL & 15)) * D_DIM +
                              kt * 32 + (LL >> 4) * 8;
                pre[i] = *(const uint4*)(src + elem);
            }
        }

#pragma unroll
        for (int tl = 0; tl < 4; ++tl) {
            const int tb = tl * 2048;        // ushort offset of tile
            short8 bh0 = *(const short8*)(stage + tb +    0 + L * 8);
            short8 bh1 = *(const short8*)(stage + tb +  512 + L * 8);
            short8 bl0 = *(const short8*)(stage + tb + 1024 + L * 8);
            short8 bl1 = *(const short8*)(stage + tb + 1536 + L * 8);

            // 4 independent chains of depth 3 (was 2 chains of depth 6)
            f32x4 p0 = {0.f,0.f,0.f,0.f}, q0 = {0.f,0.f,0.f,0.f};
            f32x4 p1 = {0.f,0.f,0.f,0.f}, q1 = {0.f,0.f,0.f,0.f};
            p0 = __builtin_amdgcn_mfma_f32_16x16x32_bf16(ah[0][0], bh0, p0, 0, 0, 0);
            p1 = __builtin_amdgcn_mfma_f32_16x16x32_bf16(ah[1][0], bh0, p1, 0, 0, 0);
            q0 = __builtin_amdgcn_mfma_f32_16x16x32_bf16(ah[0][1], bl1, q0, 0, 0, 0);
            q1 = __builtin_amdgcn_mfma_f32_16x16x32_bf16(ah[1][1], bl1, q1, 0, 0, 0);
            p0 = __builtin_amdgcn_mfma_f32_16x16x32_bf16(ah[0][1], bh1, p0, 0, 0, 0);
            p1 = __builtin_amdgcn_mfma_f32_16x16x32_bf16(ah[1][1], bh1, p1, 0, 0, 0);
            q0 = __builtin_amdgcn_mfma_f32_16x16x32_bf16(al[0][0], bh0, q0, 0, 0, 0);
            q1 = __builtin_amdgcn_mfma_f32_16x16x32_bf16(al[1][0], bh0, q1, 0, 0, 0);
            p0 = __builtin_amdgcn_mfma_f32_16x16x32_bf16(ah[0][0], bl0, p0, 0, 0, 0);
            p1 = __builtin_amdgcn_mfma_f32_16x16x32_bf16(ah[1][0], bl0, p1, 0, 0, 0);
            q0 = __builtin_amdgcn_mfma_f32_16x16x32_bf16(al[0][1], bh1, q0, 0, 0, 0);
            q1 = __builtin_amdgcn_mfma_f32_16x16x32_bf16(al[1][1], bh1, q1, 0, 0, 0);
            f32x4 s0 = p0 + q0;
            f32x4 s1 = p1 + q1;

            int tg = r * 4 + tl;             // global tile 0..63
            float cv = csq_s[tg * 16 + n];
            uintT kcp = (uintT)(63 - tg);    // complement -> packed max == first occurrence
#pragma unroll
            for (int j = 0; j < 4; ++j) {
                float v0 = fmaf(2.0f, s0[j], -cv);
                int u0 = (int)((__float_as_uint(v0) & 0xFFFFFFC0u) | kcp);
                m2p[0][j] = max(m2p[0][j], min(m1p[0][j], u0));
                m1p[0][j] = max(m1p[0][j], u0);
                float v1 = fmaf(2.0f, s1[j], -cv);
                int u1 = (int)((__float_as_uint(v1) & 0xFFFFFFC0u) | kcp);
                m2p[1][j] = max(m2p[1][j], min(m1p[1][j], u1));
                m1p[1][j] = max(m1p[1][j], u1);
            }
        }
    }

    // ---- decode + butterfly reduce across the 16 classes (max-space) ----
#pragma unroll
    for (int s = 0; s < 2; ++s)
#pragma unroll
        for (int j = 0; j < 4; ++j) {
            int p1i = m1p[s][j], p2i = m2p[s][j];
            float a1 = __uint_as_float((uintT)p1i & 0xFFFFFFC0u);
            float a2 = __uint_as_float((uintT)p2i & 0xFFFFFFC0u);
            int ai = ((63 - (p1i & 63)) << 4) | n;   // idx = tl*16 + n
#pragma unroll
            for (int msk = 1; msk < 16; msk <<= 1) {
                float o1 = __shfl_xor(a1, msk);
                float o2 = __shfl_xor(a2, msk);
                int oi = __shfl_xor(ai, msk);
                float nm2 = fmaxf(fminf(a1, o1), fmaxf(a2, o2));
                bool take = (o1 > a1) || (o1 == a1 && oi < ai);
                a1 = take ? o1 : a1;
                ai = take ? oi : ai;
                a2 = nm2;
            }
            if (n == 0) {
                int rl = w * 32 + s * 16 + q * 4 + j;
                float xsq = xsq_s[rl];
                float xn = sqrtf(xsq);
                // 2*margin (validated: 8e-5*xn + 4e-4) + 2*quant (2^-12)
                float thr = fmaf(8.0e-5f, xn, 6.44140625e-4f);
                bool fb = ((a1 - a2) <= thr) || (a2 < 0.0f) || (xsq > 170.0f);
                idx_s[rl] = ai | (fb ? (1 << 30) : 0);
            }
        }
    __syncthreads();

    // ---- outputs (plain stores; round-5 nt stores 4x'd WRITE_SIZE) ----
    if (t < 128) {
        int e = idx_s[t];
        int row = blockIdx.x * 128 + t;
        out_idx[row] = (float)(e & 0x3FFFFFFF);
        if (e >> 30) {
            int pos = atomicAdd(cnt, 1);
            if (pos < WL_CAP) wl[pos] = row;
        }
    }
    {
        int lr = t >> 1;
        int row = blockIdx.x * 128 + lr;
        int seg = (t & 1) * 32;
        int id = idx_s[lr] & 0x3FFFFFFF;
        const float4* xs = (const float4*)(x_all + (size_t)row * D_DIM + seg);
        const float4* cs = (const float4*)(cb + (size_t)id * D_DIM + seg);
        float4* rs = (float4*)(out_res + (size_t)row * D_DIM + seg);
        float4* es = (float4*)(out_emb + (size_t)row * D_DIM + seg);
#pragma unroll
        for (int j = 0; j < 8; ++j) {
            float4 xv = xs[j], cv = cs[j];
            float4 rv;
            rv.x = xv.x - cv.x; rv.y = xv.y - cv.y;
            rv.z = xv.z - cv.z; rv.w = xv.w - cv.w;
            rs[j] = rv;
            es[j] = cv;
        }
    }
}

// ---------------------------------------------------------------------------
// Fallback: exact fp32 rescan of worklist rows (unchanged, validated).
// ---------------------------------------------------------------------------
__global__ __launch_bounds__(256) void fallback_kernel(
        const float* __restrict__ x_all, const float* __restrict__ cb,
        const float* __restrict__ c_sq, const int* __restrict__ wl,
        const int* __restrict__ cnt,
        float* __restrict__ out_idx, float* __restrict__ out_res,
        float* __restrict__ out_emb) {
    int count = *cnt;
    if (count > WL_CAP) count = WL_CAP;
    const int L = threadIdx.x & 63;
    const int waveId = blockIdx.x * 4 + (threadIdx.x >> 6);
    const int nWaves = gridDim.x * 4;

    for (int i = waveId; i < count; i += nWaves) {
        int r = wl[i];

        float x[D_DIM];
        const float4* xr = (const float4*)(x_all + (size_t)r * D_DIM);
#pragma unroll
        for (int j = 0; j < D_DIM / 4; ++j) {
            float4 v = xr[j];
            x[4 * j + 0] = v.x; x[4 * j + 1] = v.y;
            x[4 * j + 2] = v.z; x[4 * j + 3] = v.w;
        }
        float x_sq = 0.0f;
#pragma unroll
        for (int d = 0; d < D_DIM; ++d) x_sq = fmaf(x[d], x[d], x_sq);

        float best = INFINITY;
        int bidx = 0x7FFFFFFF;
        for (int kk = 0; kk < 16; ++kk) {
            int k = kk * 64 + L;
            const float* c0 = cb + (size_t)k * D_DIM;
            float a00 = 0.f, a01 = 0.f, a02 = 0.f, a03 = 0.f;
#pragma unroll
            for (int j = 0; j < 4; ++j) {
                float4 v0 = *(const float4*)(c0 + 16 * j + 0);
                float4 v1 = *(const float4*)(c0 + 16 * j + 4);
                float4 v2 = *(const float4*)(c0 + 16 * j + 8);
                float4 v3 = *(const float4*)(c0 + 16 * j + 12);
                float* a = (j == 0) ? &a00 : (j == 1) ? &a01 : (j == 2) ? &a02 : &a03;
                float acc = *a;
                acc = fmaf(x[16 * j + 0],  v0.x, acc);
                acc = fmaf(x[16 * j + 1],  v0.y, acc);
                acc = fmaf(x[16 * j + 2],  v0.z, acc);
                acc = fmaf(x[16 * j + 3],  v0.w, acc);
                acc = fmaf(x[16 * j + 4],  v1.x, acc);
                acc = fmaf(x[16 * j + 5],  v1.y, acc);
                acc = fmaf(x[16 * j + 6],  v1.z, acc);
                acc = fmaf(x[16 * j + 7],  v1.w, acc);
                acc = fmaf(x[16 * j + 8],  v2.x, acc);
                acc = fmaf(x[16 * j + 9],  v2.y, acc);
                acc = fmaf(x[16 * j + 10], v2.z, acc);
                acc = fmaf(x[16 * j + 11], v2.w, acc);
                acc = fmaf(x[16 * j + 12], v3.x, acc);
                acc = fmaf(x[16 * j + 13], v3.y, acc);
                acc = fmaf(x[16 * j + 14], v3.z, acc);
                acc = fmaf(x[16 * j + 15], v3.w, acc);
                *a = acc;
            }
            float dot = (a00 + a01) + (a02 + a03);
            float d = (x_sq - 2.0f * dot) + c_sq[k];
            if (d < best) { best = d; bidx = k; }
        }

#pragma unroll
        for (int msk = 1; msk < 64; msk <<= 1) {
            float ob = __shfl_xor(best, msk);
            int oi = __shfl_xor(bidx, msk);
            bool take = (ob < best) || (ob == best && oi < bidx);
            best = take ? ob : best;
            bidx = take ? oi : bidx;
        }

        if (L < 16) {
            const float4* cbest = (const float4*)(cb + (size_t)bidx * D_DIM);
            float4 c = cbest[L];
            float4 v;
            v.x = x[4 * L + 0] - c.x; v.y = x[4 * L + 1] - c.y;
            v.z = x[4 * L + 2] - c.z; v.w = x[4 * L + 3] - c.w;
            ((float4*)(out_res + (size_t)r * D_DIM))[L] = v;
            ((float4*)(out_emb + (size_t)r * D_DIM))[L] = c;
            if (L == 0) out_idx[r] = (float)bidx;
        }
    }
}

extern "C" void kernel_launch(void* const* d_in, const int* in_sizes, int n_in,
                              void* d_out, int out_size, void* d_ws, size_t ws_size,
                              hipStream_t stream) {
    const float* x  = (const float*)d_in[0];
    const float* cb = (const float*)d_in[1];

    char* base = (char*)d_ws;
    ushortT* cbh = (ushortT*)base;                         // 128 KB
    ushortT* cbl = (ushortT*)(base + 131072);              // 128 KB
    float*   csq = (float*)(base + 262144);                // 4 KB
    int*     cnt = (int*)(base + 266240);
    int*     wl  = (int*)(base + 266256);                  // 1 MB (cap == N)

    float* out   = (float*)d_out;
    float* o_idx = out;
    float* o_res = out + (size_t)N_ROWS;
    float* o_emb = o_res + (size_t)N_ROWS * D_DIM;

    prep_kernel<<<16, 64, 0, stream>>>(cb, cbh, cbl, csq, cnt);
    coarse_kernel<<<N_ROWS / 128, 256, 0, stream>>>(x, cb, cbh, cbl, csq,
                                                    o_idx, o_res, o_emb, cnt, wl);
    fallback_kernel<<<1024, 256, 0, stream>>>(x, cb, csq, wl, cnt,
                                              o_idx, o_res, o_emb);
}